// Round 1
// baseline (1021.054 us; speedup 1.0000x reference)
//
#include <hip/hip_runtime.h>

#define B_   8
#define L_   8192
#define BL_  65536      // B*L
#define DM_  128
#define DI_  256
#define DS_  16
#define NCH_ 128        // scan chunks
#define CHK_ 64         // L_/NCH_
#define EPS_ 1e-5f

// ---------------- rmsnorm row scale: rs[row] = rsqrt(mean(h^2)+eps) ----------------
__global__ __launch_bounds__(256) void k_rowscale(const float* __restrict__ h, float* __restrict__ rs) {
    int row  = blockIdx.x * 4 + (threadIdx.x >> 6);
    int lane = threadIdx.x & 63;
    float2 v = *(const float2*)(h + (size_t)row * DM_ + lane * 2);
    float ss = v.x * v.x + v.y * v.y;
    #pragma unroll
    for (int o = 1; o < 64; o <<= 1) ss += __shfl_xor(ss, o, 64);
    if (lane == 0) rs[row] = rsqrtf(ss * (1.0f / DM_) + EPS_);
}

// ---------------- final rmsnorm (in-place on h, writes h*scale*w) ----------------
__global__ __launch_bounds__(256) void k_finalnorm(float* h, const float* __restrict__ w) {
    int row  = blockIdx.x * 4 + (threadIdx.x >> 6);
    int lane = threadIdx.x & 63;
    float* p = h + (size_t)row * DM_ + lane * 2;
    float2 v = *(const float2*)p;
    float ss = v.x * v.x + v.y * v.y;
    #pragma unroll
    for (int o = 1; o < 64; o <<= 1) ss += __shfl_xor(ss, o, 64);
    float sc = rsqrtf(ss * (1.0f / DM_) + EPS_);
    float2 wv = *(const float2*)(w + lane * 2);
    v.x *= sc * wv.x; v.y *= sc * wv.y;
    *(float2*)p = v;
}

// ---------------- generic fp32 GEMM: C[M,N] = A[M,K] @ W[N,K]^T ----------------
// VARIANT 0: A scaled by rs[row]*nw[k] (fused rmsnorm) -> proj
// VARIANT 1: plain, store cols < NW only (x_proj, NW=40 zero-padded to 64)
// VARIANT 2: C = resid + acc (out_proj + residual)
template<int VARIANT, int K, int NBLK, int NW, int LDC>
__global__ __launch_bounds__(256) void k_gemm(
    const float* __restrict__ A, const float* __restrict__ W,
    float* C, const float* __restrict__ rs, const float* __restrict__ nw,
    const float* resid)
{
    __shared__ __align__(16) float As[64][68];   // [k][m], +4 pad keeps 16B alignment
    __shared__ __align__(16) float Ws[64][68];   // [k][n]
    int tid = threadIdx.x;
    int bn = blockIdx.x % NBLK;
    int bm = blockIdx.x / NBLK;
    int row0 = bm * 64, col0 = bn * 64;
    int lr  = tid >> 4;          // 0..15
    int lc4 = (tid & 15) * 4;    // 0..60
    int tm  = tid >> 4, tn = tid & 15;
    float acc[4][4] = {};
    for (int k0 = 0; k0 < K; k0 += 64) {
        if (k0) __syncthreads();
        #pragma unroll
        for (int s = 0; s < 4; ++s) {
            int m = s * 16 + lr;
            float4 v = *(const float4*)(A + (size_t)(row0 + m) * K + k0 + lc4);
            if (VARIANT == 0) {
                float r = rs[row0 + m];
                v.x *= r * nw[k0 + lc4 + 0];
                v.y *= r * nw[k0 + lc4 + 1];
                v.z *= r * nw[k0 + lc4 + 2];
                v.w *= r * nw[k0 + lc4 + 3];
            }
            As[lc4 + 0][m] = v.x; As[lc4 + 1][m] = v.y;
            As[lc4 + 2][m] = v.z; As[lc4 + 3][m] = v.w;
        }
        #pragma unroll
        for (int s = 0; s < 4; ++s) {
            int n = s * 16 + lr;
            float4 v;
            if ((NW & 63) && (col0 + n) >= NW) v = make_float4(0.f, 0.f, 0.f, 0.f);
            else v = *(const float4*)(W + (size_t)(col0 + n) * K + k0 + lc4);
            Ws[lc4 + 0][n] = v.x; Ws[lc4 + 1][n] = v.y;
            Ws[lc4 + 2][n] = v.z; Ws[lc4 + 3][n] = v.w;
        }
        __syncthreads();
        #pragma unroll
        for (int k = 0; k < 64; ++k) {
            float4 av = *(const float4*)&As[k][tm * 4];
            float4 wv = *(const float4*)&Ws[k][tn * 4];
            float a4[4] = {av.x, av.y, av.z, av.w};
            float w4[4] = {wv.x, wv.y, wv.z, wv.w};
            #pragma unroll
            for (int i = 0; i < 4; ++i)
                #pragma unroll
                for (int j = 0; j < 4; ++j)
                    acc[i][j] = fmaf(a4[i], w4[j], acc[i][j]);
        }
    }
    #pragma unroll
    for (int i = 0; i < 4; ++i) {
        int row = row0 + tm * 4 + i;
        #pragma unroll
        for (int j = 0; j < 4; ++j) {
            int col = col0 + tn * 4 + j;
            if ((NW & 63) && col >= NW) continue;
            float v = acc[i][j];
            if (VARIANT == 2) v += resid[(size_t)row * LDC + col];
            C[(size_t)row * LDC + col] = v;
        }
    }
}

// ---------------- causal depthwise conv (D_CONV=4) + bias + silu ----------------
// reads xh = proj[:, 0:256] (row stride 512), writes xc (row stride 256)
__global__ __launch_bounds__(256) void k_conv(
    const float* __restrict__ proj, const float* __restrict__ cw,
    const float* __restrict__ cb, float* __restrict__ xc)
{
    int e  = threadIdx.x;
    int b  = blockIdx.y;
    int t0 = blockIdx.x * 64;
    float w0 = cw[e*4+0], w1 = cw[e*4+1], w2 = cw[e*4+2], w3 = cw[e*4+3];
    float bias = cb[e];
    const float* src = proj + ((size_t)b * L_) * 512 + e;
    float x0 = (t0 >= 3) ? src[(size_t)(t0-3)*512] : 0.f;
    float x1 = (t0 >= 2) ? src[(size_t)(t0-2)*512] : 0.f;
    float x2 = (t0 >= 1) ? src[(size_t)(t0-1)*512] : 0.f;
    float* dst = xc + ((size_t)b * L_ + t0) * 256 + e;
    for (int i = 0; i < 64; ++i) {
        float x3 = src[(size_t)(t0 + i) * 512];
        float v = fmaf(w0,x0, fmaf(w1,x1, fmaf(w2,x2, fmaf(w3,x3, bias))));
        dst[(size_t)i * 256] = v / (1.f + __expf(-v));
        x0 = x1; x1 = x2; x2 = x3;
    }
}

// ---------------- dt = softplus(dt_r @ dtw^T + dtb), written into proj cols 0..255 ----------------
__global__ __launch_bounds__(256) void k_dtproj(
    const float* __restrict__ ssm, const float* __restrict__ dtw,
    const float* __restrict__ dtb, float* __restrict__ dtz)
{
    __shared__ float dtr[16][8];
    int tid = threadIdx.x;
    size_t base = (size_t)blockIdx.x * 16;
    if (tid < 128) dtr[tid >> 3][tid & 7] = ssm[(base + (tid >> 3)) * 40 + (tid & 7)];
    float w[8];
    #pragma unroll
    for (int k = 0; k < 8; ++k) w[k] = dtw[tid * 8 + k];
    float bias = dtb[tid];
    __syncthreads();
    #pragma unroll
    for (int r = 0; r < 16; ++r) {
        float acc = bias;
        #pragma unroll
        for (int k = 0; k < 8; ++k) acc = fmaf(dtr[r][k], w[k], acc);
        float sp = (acc > 20.f) ? acc : __logf(1.f + __expf(acc));
        dtz[(base + r) * 512 + tid] = sp;
    }
}

// ---------------- scan pass 1: per-chunk (prod a, h_end) with h0=0 ----------------
__global__ __launch_bounds__(256) void k_scan1(
    const float* __restrict__ dtz, const float* __restrict__ xc,
    const float* __restrict__ ssm, const float* __restrict__ alog,
    float* __restrict__ ap, float* __restrict__ he)
{
    int gid = blockIdx.x * 256 + threadIdx.x;
    int d = gid & 255;
    int b = (gid >> 8) & 7;
    int c = gid >> 11;
    float negA[16];
    #pragma unroll
    for (int s = 0; s < 16; ++s) negA[s] = -__expf(alog[d * 16 + s]);
    float h[16] = {}, pr[16];
    #pragma unroll
    for (int s = 0; s < 16; ++s) pr[s] = 1.f;
    size_t row0 = (size_t)b * L_ + (size_t)c * CHK_;
    for (int t = 0; t < CHK_; ++t) {
        size_t r = row0 + t;
        float ldt = dtz[r * 512 + d];
        float lx  = xc[r * 256 + d];
        float u0  = ldt * lx;
        const float4* bp = (const float4*)(ssm + r * 40 + 8);
        float4 q0 = bp[0], q1 = bp[1], q2 = bp[2], q3 = bp[3];
        float Bv[16] = {q0.x,q0.y,q0.z,q0.w,q1.x,q1.y,q1.z,q1.w,
                        q2.x,q2.y,q2.z,q2.w,q3.x,q3.y,q3.z,q3.w};
        #pragma unroll
        for (int s = 0; s < 16; ++s) {
            float a = __expf(ldt * negA[s]);
            h[s] = fmaf(a, h[s], u0 * Bv[s]);
            pr[s] *= a;
        }
    }
    size_t o = ((size_t)c * 2048 + (size_t)b * 256 + d) * 16;
    #pragma unroll
    for (int s = 0; s < 16; ++s) { ap[o + s] = pr[s]; he[o + s] = h[s]; }
}

// ---------------- scan pass 2: chunk-carry scan, writes h_in per chunk ----------------
__global__ __launch_bounds__(256) void k_scan2(
    const float* __restrict__ ap, const float* __restrict__ he,
    float* __restrict__ hin)
{
    int gid = blockIdx.x * 256 + threadIdx.x;   // (b,d,s) flat, 32768 lanes
    float h = 0.f;
    for (int c = 0; c < NCH_; ++c) {
        size_t idx = (size_t)c * 32768 + gid;
        hin[idx] = h;
        h = fmaf(ap[idx], h, he[idx]);
    }
}

// ---------------- scan pass 3: replay with h_in, fuse y = (ys + xc*D)*silu(z), in-place on xc ----------------
__global__ __launch_bounds__(256) void k_scan3(
    const float* __restrict__ dtz, float* xc,
    const float* __restrict__ ssm, const float* __restrict__ alog,
    const float* __restrict__ hin, const float* __restrict__ dskip)
{
    int gid = blockIdx.x * 256 + threadIdx.x;
    int d = gid & 255;
    int b = (gid >> 8) & 7;
    int c = gid >> 11;
    float negA[16];
    #pragma unroll
    for (int s = 0; s < 16; ++s) negA[s] = -__expf(alog[d * 16 + s]);
    float h[16];
    size_t o = ((size_t)c * 2048 + (size_t)b * 256 + d) * 16;
    #pragma unroll
    for (int s = 0; s < 16; ++s) h[s] = hin[o + s];
    float dsk = dskip[d];
    size_t row0 = (size_t)b * L_ + (size_t)c * CHK_;
    for (int t = 0; t < CHK_; ++t) {
        size_t r = row0 + t;
        float ldt = dtz[r * 512 + d];
        float z   = dtz[r * 512 + 256 + d];
        float lx  = xc[r * 256 + d];
        float u0  = ldt * lx;
        const float4* bp = (const float4*)(ssm + r * 40 + 8);
        float4 q0 = bp[0], q1 = bp[1], q2 = bp[2], q3 = bp[3];
        const float4* cp = (const float4*)(ssm + r * 40 + 24);
        float4 p0 = cp[0], p1 = cp[1], p2 = cp[2], p3 = cp[3];
        float Bv[16] = {q0.x,q0.y,q0.z,q0.w,q1.x,q1.y,q1.z,q1.w,
                        q2.x,q2.y,q2.z,q2.w,q3.x,q3.y,q3.z,q3.w};
        float Cv[16] = {p0.x,p0.y,p0.z,p0.w,p1.x,p1.y,p1.z,p1.w,
                        p2.x,p2.y,p2.z,p2.w,p3.x,p3.y,p3.z,p3.w};
        float y = 0.f;
        #pragma unroll
        for (int s = 0; s < 16; ++s) {
            float a = __expf(ldt * negA[s]);
            h[s] = fmaf(a, h[s], u0 * Bv[s]);
            y = fmaf(h[s], Cv[s], y);
        }
        y = fmaf(lx, dsk, y);
        float g = z / (1.f + __expf(-z));
        xc[r * 256 + d] = y * g;
    }
}

extern "C" void kernel_launch(void* const* d_in, const int* in_sizes, int n_in,
                              void* d_out, int out_size, void* d_ws, size_t ws_size,
                              hipStream_t stream) {
    (void)in_sizes; (void)n_in; (void)out_size; (void)ws_size;
    const float* x       = (const float*)d_in[0];
    const float* norm_w  = (const float*)d_in[1];
    const float* in_w    = (const float*)d_in[2];
    const float* conv_w  = (const float*)d_in[3];
    const float* conv_b  = (const float*)d_in[4];
    const float* xp_w    = (const float*)d_in[5];
    const float* dt_w    = (const float*)d_in[6];
    const float* dt_b    = (const float*)d_in[7];
    const float* A_log   = (const float*)d_in[8];
    const float* D_skip  = (const float*)d_in[9];
    const float* out_w   = (const float*)d_in[10];
    const float* normf_w = (const float*)d_in[11];
    float* h  = (float*)d_out;                      // residual stream lives in d_out
    float* ws = (float*)d_ws;

    // workspace layout (fp32), total ~262 MB
    float* rs   = ws;                               // 65536
    float* proj = rs + BL_;                         // BL*512 (xh|z); dt overwrites cols 0..255 later
    float* xcb  = proj + (size_t)BL_ * 512;         // BL*256 (conv out, then gated y in-place)
    float* ssm  = xcb + (size_t)BL_ * 256;          // BL*40  (dt_r | B | C)
    float* ap   = ssm + (size_t)BL_ * 40;           // NCH*32768
    float* he   = ap + (size_t)NCH_ * 32768;        // NCH*32768
    float* hin  = he + (size_t)NCH_ * 32768;        // NCH*32768

    for (int l = 0; l < 2; ++l) {
        const float* hi = l ? (const float*)h : x;
        k_rowscale<<<BL_/4, 256, 0, stream>>>(hi, rs);
        k_gemm<0,128,8,512,512><<<1024*8, 256, 0, stream>>>(
            hi, in_w + (size_t)l*512*128, proj, rs, norm_w + l*128, nullptr);
        k_conv<<<dim3(L_/64, B_), 256, 0, stream>>>(
            proj, conv_w + l*DI_*4, conv_b + l*DI_, xcb);
        k_gemm<1,256,1,40,40><<<1024, 256, 0, stream>>>(
            xcb, xp_w + (size_t)l*40*256, ssm, nullptr, nullptr, nullptr);
        k_dtproj<<<BL_/16, 256, 0, stream>>>(
            ssm, dt_w + (size_t)l*DI_*8, dt_b + l*DI_, proj);
        k_scan1<<<NCH_*B_, 256, 0, stream>>>(
            proj, xcb, ssm, A_log + (size_t)l*DI_*DS_, ap, he);
        k_scan2<<<128, 256, 0, stream>>>(ap, he, hin);
        k_scan3<<<NCH_*B_, 256, 0, stream>>>(
            proj, xcb, ssm, A_log + (size_t)l*DI_*DS_, hin, D_skip + l*DI_);
        k_gemm<2,256,2,128,128><<<1024*2, 256, 0, stream>>>(
            xcb, out_w + (size_t)l*DM_*DI_, h, nullptr, nullptr, hi);
    }
    k_finalnorm<<<BL_/4, 256, 0, stream>>>(h, normf_w);
}

// Round 2
// 593.638 us; speedup vs baseline: 1.7200x; 1.7200x over previous
//
#include <hip/hip_runtime.h>

#define B_   8
#define L_   8192
#define BL_  65536      // B*L
#define DM_  128
#define DI_  256
#define DS_  16
#define NCH_ 128        // scan chunks
#define CHK_ 64         // L_/NCH_
#define EPS_ 1e-5f
#define KC_  128        // GEMM K-chunk staged in LDS

typedef __attribute__((ext_vector_type(8))) short short8;
typedef __attribute__((ext_vector_type(4))) float f32x4;

static __device__ __forceinline__ unsigned short f2bf(float f) {
    union { float f; unsigned int u; } v; v.f = f;
    unsigned int r = (v.u + 0x7fffu + ((v.u >> 16) & 1u)) >> 16;
    return (unsigned short)r;
}
static __device__ __forceinline__ float bf2f(unsigned short u) {
    union { unsigned int u; float f; } v; v.u = ((unsigned int)u) << 16;
    return v.f;
}

// ---------------- weights -> bf16 (once per launch) ----------------
// in_w: 2*512*128 -> in16 ; out_w: 2*128*256 -> out16 ; xp_w: 2*40*256 -> xp16 padded 2*64*256
__global__ __launch_bounds__(256) void k_wcvt(
    const float* __restrict__ in_w, const float* __restrict__ out_w,
    const float* __restrict__ xp_w,
    unsigned short* __restrict__ in16, unsigned short* __restrict__ out16,
    unsigned short* __restrict__ xp16)
{
    int n = blockIdx.x * 256 + threadIdx.x;
    if (n < 131072) { in16[n] = f2bf(in_w[n]); return; }
    n -= 131072;
    if (n < 65536) { out16[n] = f2bf(out_w[n]); return; }
    n -= 65536;                      // 0..32767 : 2 layers x 64 x 256
    int l = n >> 14, rk = n & 16383, r = rk >> 8, k = rk & 255;
    xp16[n] = (r < 40) ? f2bf(xp_w[l * 10240 + r * 256 + k]) : (unsigned short)0;
}

// ---------------- fused rmsnorm -> bf16: o16[row] = bf16(h*rsqrt(mean h^2+eps)*w) ----------------
__global__ __launch_bounds__(256) void k_normcvt(
    const float* __restrict__ h, const float* __restrict__ w,
    unsigned short* __restrict__ o16)
{
    int row  = blockIdx.x * 4 + (threadIdx.x >> 6);
    int lane = threadIdx.x & 63;
    float2 v = *(const float2*)(h + (size_t)row * DM_ + lane * 2);
    float ss = v.x * v.x + v.y * v.y;
    #pragma unroll
    for (int o = 1; o < 64; o <<= 1) ss += __shfl_xor(ss, o, 64);
    float sc = rsqrtf(ss * (1.0f / DM_) + EPS_);
    float2 wv = *(const float2*)(w + lane * 2);
    union { unsigned short s[2]; unsigned int u; } o;
    o.s[0] = f2bf(v.x * sc * wv.x);
    o.s[1] = f2bf(v.y * sc * wv.y);
    *(unsigned int*)(o16 + (size_t)row * DM_ + lane * 2) = o.u;
}

// ---------------- final rmsnorm (in-place fp32) ----------------
__global__ __launch_bounds__(256) void k_finalnorm(float* h, const float* __restrict__ w) {
    int row  = blockIdx.x * 4 + (threadIdx.x >> 6);
    int lane = threadIdx.x & 63;
    float* p = h + (size_t)row * DM_ + lane * 2;
    float2 v = *(const float2*)p;
    float ss = v.x * v.x + v.y * v.y;
    #pragma unroll
    for (int o = 1; o < 64; o <<= 1) ss += __shfl_xor(ss, o, 64);
    float sc = rsqrtf(ss * (1.0f / DM_) + EPS_);
    float2 wv = *(const float2*)(w + lane * 2);
    v.x *= sc * wv.x; v.y *= sc * wv.y;
    *(float2*)p = v;
}

// ---------------- bf16 MFMA GEMM: C[M,NW] = A16[M,K] @ W16[N,K]^T (+resid) ----------------
// block tile 128 x BN, 4 waves, LDS XOR-swizzled (c16 ^= row&7 on 16B units)
template<int K, int BN, int NW, int LDC, bool RESID>
__global__ __launch_bounds__(256) void k_mgemm(
    const unsigned short* __restrict__ A16, const unsigned short* __restrict__ W16,
    float* __restrict__ C, const float* __restrict__ resid)
{
    constexpr int NBN = (NW + BN - 1) / BN;
    constexpr int WM  = (BN == 128) ? 4 : 2;
    __shared__ __align__(16) unsigned short lA[128 * KC_];
    __shared__ __align__(16) unsigned short lB[BN * KC_];
    int tid  = threadIdx.x;
    int bn   = blockIdx.x % NBN;
    int bm   = blockIdx.x / NBN;
    int row0 = bm * 128, col0 = bn * BN;
    int wid  = tid >> 6, lane = tid & 63;
    int wm0  = (BN == 128) ? (wid >> 1) * 64 : wid * 32;
    int wn0  = (BN == 128) ? (wid & 1) * 64 : 0;
    int lg   = lane >> 4, ln = lane & 15;

    f32x4 acc[WM][4];
    #pragma unroll
    for (int i = 0; i < WM; ++i)
        #pragma unroll
        for (int j = 0; j < 4; ++j) acc[i][j] = (f32x4){0.f, 0.f, 0.f, 0.f};

    for (int k0 = 0; k0 < K; k0 += KC_) {
        if (k0) __syncthreads();
        #pragma unroll
        for (int i = 0; i < 8; ++i) {                       // A: 128 rows x 16 units
            int u = tid + i * 256, r = u >> 4, c = u & 15;
            *(uint4*)&lA[r * KC_ + (c ^ (r & 7)) * 8] =
                *(const uint4*)(A16 + (size_t)(row0 + r) * K + k0 + c * 8);
        }
        #pragma unroll
        for (int i = 0; i < (BN * 16) / 256; ++i) {         // B: BN rows x 16 units
            int u = tid + i * 256, r = u >> 4, c = u & 15;
            *(uint4*)&lB[r * KC_ + (c ^ (r & 7)) * 8] =
                *(const uint4*)(W16 + (size_t)(col0 + r) * K + k0 + c * 8);
        }
        __syncthreads();
        #pragma unroll
        for (int kk = 0; kk < 4; ++kk) {
            int cb = kk * 4 + lg;
            short8 a[WM], b[4];
            #pragma unroll
            for (int f = 0; f < WM; ++f) {
                int r = wm0 + f * 16 + ln;
                a[f] = *(const short8*)&lA[r * KC_ + (cb ^ (r & 7)) * 8];
            }
            #pragma unroll
            for (int f = 0; f < 4; ++f) {
                int r = wn0 + f * 16 + ln;
                b[f] = *(const short8*)&lB[r * KC_ + (cb ^ (r & 7)) * 8];
            }
            #pragma unroll
            for (int i = 0; i < WM; ++i)
                #pragma unroll
                for (int j = 0; j < 4; ++j)
                    acc[i][j] = __builtin_amdgcn_mfma_f32_16x16x32_bf16(a[i], b[j], acc[i][j], 0, 0, 0);
        }
    }
    #pragma unroll
    for (int i = 0; i < WM; ++i) {
        #pragma unroll
        for (int j = 0; j < 4; ++j) {
            int gcol = col0 + wn0 + j * 16 + ln;
            if ((NW % BN) && gcol >= NW) continue;
            #pragma unroll
            for (int r = 0; r < 4; ++r) {
                int grow = row0 + wm0 + i * 16 + 4 * lg + r;
                float v = acc[i][j][r];
                if (RESID) v += resid[(size_t)grow * LDC + gcol];
                C[(size_t)grow * LDC + gcol] = v;
            }
        }
    }
}

// ---------------- causal depthwise conv (D_CONV=4) + bias + silu -> bf16 ----------------
__global__ __launch_bounds__(256) void k_conv(
    const float* __restrict__ proj, const float* __restrict__ cw,
    const float* __restrict__ cb, unsigned short* __restrict__ xc16)
{
    int e  = threadIdx.x;
    int b  = blockIdx.y;
    int t0 = blockIdx.x * 64;
    float w0 = cw[e*4+0], w1 = cw[e*4+1], w2 = cw[e*4+2], w3 = cw[e*4+3];
    float bias = cb[e];
    const float* src = proj + ((size_t)b * L_) * 512 + e;
    float x0 = (t0 >= 3) ? src[(size_t)(t0-3)*512] : 0.f;
    float x1 = (t0 >= 2) ? src[(size_t)(t0-2)*512] : 0.f;
    float x2 = (t0 >= 1) ? src[(size_t)(t0-1)*512] : 0.f;
    unsigned short* dst = xc16 + ((size_t)b * L_ + t0) * 256 + e;
    for (int i = 0; i < 64; ++i) {
        float x3 = src[(size_t)(t0 + i) * 512];
        float v = fmaf(w0,x0, fmaf(w1,x1, fmaf(w2,x2, fmaf(w3,x3, bias))));
        dst[(size_t)i * 256] = f2bf(v / (1.f + __expf(-v)));
        x0 = x1; x1 = x2; x2 = x3;
    }
}

// ---------------- dt = softplus(dt_r @ dtw^T + dtb) -> proj cols 0..255 (fp32) ----------------
__global__ __launch_bounds__(256) void k_dtproj(
    const float* __restrict__ ssm, const float* __restrict__ dtw,
    const float* __restrict__ dtb, float* __restrict__ dtz)
{
    __shared__ float dtr[16][8];
    int tid = threadIdx.x;
    size_t base = (size_t)blockIdx.x * 16;
    if (tid < 128) dtr[tid >> 3][tid & 7] = ssm[(base + (tid >> 3)) * 40 + (tid & 7)];
    float w[8];
    #pragma unroll
    for (int k = 0; k < 8; ++k) w[k] = dtw[tid * 8 + k];
    float bias = dtb[tid];
    __syncthreads();
    #pragma unroll
    for (int r = 0; r < 16; ++r) {
        float acc = bias;
        #pragma unroll
        for (int k = 0; k < 8; ++k) acc = fmaf(dtr[r][k], w[k], acc);
        float sp = (acc > 20.f) ? acc : __logf(1.f + __expf(acc));
        dtz[(base + r) * 512 + tid] = sp;
    }
}

// ---------------- scan pass 1: per-chunk (prod a, h_end), h0=0 ----------------
__global__ __launch_bounds__(256) void k_scan1(
    const float* __restrict__ dtz, const unsigned short* __restrict__ xc16,
    const float* __restrict__ ssm, const float* __restrict__ alog,
    float* __restrict__ ap, float* __restrict__ he)
{
    int gid = blockIdx.x * 256 + threadIdx.x;
    int d = gid & 255;
    int b = (gid >> 8) & 7;
    int c = gid >> 11;
    float negA[16];
    #pragma unroll
    for (int s = 0; s < 16; ++s) negA[s] = -__expf(alog[d * 16 + s]);
    float h[16] = {}, pr[16];
    #pragma unroll
    for (int s = 0; s < 16; ++s) pr[s] = 1.f;
    size_t row0 = (size_t)b * L_ + (size_t)c * CHK_;
    for (int t = 0; t < CHK_; ++t) {
        size_t r = row0 + t;
        float ldt = dtz[r * 512 + d];
        float lx  = bf2f(xc16[r * 256 + d]);
        float u0  = ldt * lx;
        const float4* bp = (const float4*)(ssm + r * 40 + 8);
        float4 q0 = bp[0], q1 = bp[1], q2 = bp[2], q3 = bp[3];
        float Bv[16] = {q0.x,q0.y,q0.z,q0.w,q1.x,q1.y,q1.z,q1.w,
                        q2.x,q2.y,q2.z,q2.w,q3.x,q3.y,q3.z,q3.w};
        #pragma unroll
        for (int s = 0; s < 16; ++s) {
            float a = __expf(ldt * negA[s]);
            h[s] = fmaf(a, h[s], u0 * Bv[s]);
            pr[s] *= a;
        }
    }
    size_t o = ((size_t)c * 2048 + (size_t)b * 256 + d) * 16;
    #pragma unroll
    for (int s = 0; s < 16; ++s) { ap[o + s] = pr[s]; he[o + s] = h[s]; }
}

// ---------------- scan pass 2: chunk-carry scan ----------------
__global__ __launch_bounds__(256) void k_scan2(
    const float* __restrict__ ap, const float* __restrict__ he,
    float* __restrict__ hin)
{
    int gid = blockIdx.x * 256 + threadIdx.x;   // 32768 lanes = (b,d,s)
    float h = 0.f;
    for (int c = 0; c < NCH_; ++c) {
        size_t idx = (size_t)c * 32768 + gid;
        hin[idx] = h;
        h = fmaf(ap[idx], h, he[idx]);
    }
}

// ---------------- scan pass 3: replay + y=(ys+xc*D)*silu(z) -> bf16 in-place ----------------
__global__ __launch_bounds__(256) void k_scan3(
    const float* __restrict__ dtz, unsigned short* xc16,
    const float* __restrict__ ssm, const float* __restrict__ alog,
    const float* __restrict__ hin, const float* __restrict__ dskip)
{
    int gid = blockIdx.x * 256 + threadIdx.x;
    int d = gid & 255;
    int b = (gid >> 8) & 7;
    int c = gid >> 11;
    float negA[16];
    #pragma unroll
    for (int s = 0; s < 16; ++s) negA[s] = -__expf(alog[d * 16 + s]);
    float h[16];
    size_t o = ((size_t)c * 2048 + (size_t)b * 256 + d) * 16;
    #pragma unroll
    for (int s = 0; s < 16; ++s) h[s] = hin[o + s];
    float dsk = dskip[d];
    size_t row0 = (size_t)b * L_ + (size_t)c * CHK_;
    for (int t = 0; t < CHK_; ++t) {
        size_t r = row0 + t;
        float ldt = dtz[r * 512 + d];
        float z   = dtz[r * 512 + 256 + d];
        float lx  = bf2f(xc16[r * 256 + d]);
        float u0  = ldt * lx;
        const float4* bp = (const float4*)(ssm + r * 40 + 8);
        float4 q0 = bp[0], q1 = bp[1], q2 = bp[2], q3 = bp[3];
        const float4* cp = (const float4*)(ssm + r * 40 + 24);
        float4 p0 = cp[0], p1 = cp[1], p2 = cp[2], p3 = cp[3];
        float Bv[16] = {q0.x,q0.y,q0.z,q0.w,q1.x,q1.y,q1.z,q1.w,
                        q2.x,q2.y,q2.z,q2.w,q3.x,q3.y,q3.z,q3.w};
        float Cv[16] = {p0.x,p0.y,p0.z,p0.w,p1.x,p1.y,p1.z,p1.w,
                        p2.x,p2.y,p2.z,p2.w,p3.x,p3.y,p3.z,p3.w};
        float y = 0.f;
        #pragma unroll
        for (int s = 0; s < 16; ++s) {
            float a = __expf(ldt * negA[s]);
            h[s] = fmaf(a, h[s], u0 * Bv[s]);
            y = fmaf(h[s], Cv[s], y);
        }
        y = fmaf(lx, dsk, y);
        float g = z / (1.f + __expf(-z));
        xc16[r * 256 + d] = f2bf(y * g);
    }
}

extern "C" void kernel_launch(void* const* d_in, const int* in_sizes, int n_in,
                              void* d_out, int out_size, void* d_ws, size_t ws_size,
                              hipStream_t stream) {
    (void)in_sizes; (void)n_in; (void)out_size; (void)ws_size;
    const float* x       = (const float*)d_in[0];
    const float* norm_w  = (const float*)d_in[1];
    const float* in_w    = (const float*)d_in[2];
    const float* conv_w  = (const float*)d_in[3];
    const float* conv_b  = (const float*)d_in[4];
    const float* xp_w    = (const float*)d_in[5];
    const float* dt_w    = (const float*)d_in[6];
    const float* dt_b    = (const float*)d_in[7];
    const float* A_log   = (const float*)d_in[8];
    const float* D_skip  = (const float*)d_in[9];
    const float* out_w   = (const float*)d_in[10];
    const float* normf_w = (const float*)d_in[11];
    float* h = (float*)d_out;                       // residual stream lives in d_out

    // workspace layout (~246 MB)
    float* proj = (float*)d_ws;                     // BL*512 fp32 (xh|z; dt overwrites cols 0..255)
    float* ssm  = proj + (size_t)BL_ * 512;         // BL*40 fp32
    float* ap   = ssm + (size_t)BL_ * 40;           // NCH*32768
    float* he   = ap + (size_t)NCH_ * 32768;
    float* hin  = he + (size_t)NCH_ * 32768;
    unsigned short* hn16 = (unsigned short*)(hin + (size_t)NCH_ * 32768); // BL*128 bf16
    unsigned short* xc16 = hn16 + (size_t)BL_ * 128;                      // BL*256 bf16
    unsigned short* in16 = xc16 + (size_t)BL_ * 256;                      // 131072
    unsigned short* out16 = in16 + 131072;                                // 65536
    unsigned short* xp16  = out16 + 65536;                                // 32768

    k_wcvt<<<896, 256, 0, stream>>>(in_w, out_w, xp_w, in16, out16, xp16);

    for (int l = 0; l < 2; ++l) {
        const float* hi = l ? (const float*)h : x;
        k_normcvt<<<BL_/4, 256, 0, stream>>>(hi, norm_w + l * 128, hn16);
        // in_proj: (BL x 512) = hn16 (BL x 128) @ in16^T
        k_mgemm<128,128,512,512,false><<<512 * 4, 256, 0, stream>>>(
            hn16, in16 + (size_t)l * 65536, proj, nullptr);
        k_conv<<<dim3(L_/64, B_), 256, 0, stream>>>(
            proj, conv_w + l * DI_ * 4, conv_b + l * DI_, xc16);
        // x_proj: (BL x 40) = xc16 (BL x 256) @ xp16^T (padded 64 rows)
        k_mgemm<256,64,40,40,false><<<512, 256, 0, stream>>>(
            xc16, xp16 + (size_t)l * 16384, ssm, nullptr);
        k_dtproj<<<BL_/16, 256, 0, stream>>>(
            ssm, dt_w + (size_t)l * DI_ * 8, dt_b + l * DI_, proj);
        k_scan1<<<NCH_*B_, 256, 0, stream>>>(
            proj, xc16, ssm, A_log + (size_t)l * DI_ * DS_, ap, he);
        k_scan2<<<128, 256, 0, stream>>>(ap, he, hin);
        k_scan3<<<NCH_*B_, 256, 0, stream>>>(
            proj, xc16, ssm, A_log + (size_t)l * DI_ * DS_, hin, D_skip + l * DI_);
        // out_proj: h = resid + y16 (BL x 256) @ out16^T
        k_mgemm<256,128,128,128,true><<<512, 256, 0, stream>>>(
            xc16, out16 + (size_t)l * 32768, h, hi);
    }
    k_finalnorm<<<BL_/4, 256, 0, stream>>>(h, normf_w);
}